// Round 6
// baseline (262.274 us; speedup 1.0000x reference)
//
#include <hip/hip_runtime.h>

// mIoU over int32 class maps, NUM=21 (values 0..21; class 0 excluded from iou).
// out[0]=mIoU, out[1..21]=iou for classes 1..21 (f32).
//
// R6: depth-4 software pipeline on R5's structure. Joint 22x22 hist
// (1 ds_add/elem), per-wave LDS replicas, nontemporal loads; each wave keeps
// 8 int4 loads (8 KB) in flight — a load is consumed 4 iterations after
// issue. Interleaved "process slot k, reload slot k" form so regalloc keeps
// the pipeline (R3's block unroll was collapsed, VGPR=24; this is ~48).
// Non-atomic per-block partials -> 484-block reduce -> 1-wave finalize.

#define NUMC  21
#define NBINS 22
#define JBINS (NBINS * NBINS)   // 484
#define RSTR  485               // odd replica stride: spreads banks
#define NREP  4                 // one replica per wave (256 threads)
#define GRID  2048

typedef int iv4 __attribute__((ext_vector_type(4)));

__global__ void __launch_bounds__(256) hist_joint(
        const int* __restrict__ yp, const int* __restrict__ yt,
        unsigned int* __restrict__ partials, int n) {
    __shared__ unsigned int h[NREP * RSTR];
    for (int i = threadIdx.x; i < NREP * RSTR; i += 256) h[i] = 0u;
    __syncthreads();

    unsigned int* hh = h + (threadIdx.x >> 6) * RSTR;  // replica per wave

    const iv4* __restrict__ yp4 = (const iv4*)yp;
    const iv4* __restrict__ yt4 = (const iv4*)yt;
    const int n4 = n >> 2;
    const int stride = GRID * 256;
    const int i = blockIdx.x * 256 + threadIdx.x;

#define LDP(J) __builtin_nontemporal_load(yp4 + (J))
#define LDT(J) __builtin_nontemporal_load(yt4 + (J))
#define DS4(P, T)                                      \
    atomicAdd(&hh[(T).x * NBINS + (P).x], 1u);         \
    atomicAdd(&hh[(T).y * NBINS + (P).y], 1u);         \
    atomicAdd(&hh[(T).z * NBINS + (P).z], 1u);         \
    atomicAdd(&hh[(T).w * NBINS + (P).w], 1u);

    if (i + 3 * stride < n4) {
        // prologue: fill the 4-slot pipeline (8 loads in flight)
        iv4 p0 = LDP(i),              t0 = LDT(i);
        iv4 p1 = LDP(i + stride),     t1 = LDT(i + stride);
        iv4 p2 = LDP(i + 2 * stride), t2 = LDT(i + 2 * stride);
        iv4 p3 = LDP(i + 3 * stride), t3 = LDT(i + 3 * stride);
        int j = i + 4 * stride;
        for (; j + 3 * stride < n4; j += 4 * stride) {
            DS4(p0, t0) p0 = LDP(j);              t0 = LDT(j);
            DS4(p1, t1) p1 = LDP(j + stride);     t1 = LDT(j + stride);
            DS4(p2, t2) p2 = LDP(j + 2 * stride); t2 = LDT(j + 2 * stride);
            DS4(p3, t3) p3 = LDP(j + 3 * stride); t3 = LDT(j + 3 * stride);
        }
        // drain pipeline
        DS4(p0, t0) DS4(p1, t1) DS4(p2, t2) DS4(p3, t3)
        // leftover (<4) iterations
        for (; j < n4; j += stride) {
            iv4 p = LDP(j), t = LDT(j);
            DS4(p, t)
        }
    } else if (i < n4) {
        for (int j = i; j < n4; j += stride) {
            iv4 p = LDP(j), t = LDT(j);
            DS4(p, t)
        }
    }

    // tail (n % 4 != 0): one thread, into its own replica
    if (blockIdx.x == 0 && threadIdx.x == 0) {
        for (int k = n4 << 2; k < n; k++)
            atomicAdd(&hh[yt[k] * NBINS + yp[k]], 1u);
    }
#undef DS4
#undef LDP
#undef LDT

    __syncthreads();
    // sum the 4 replicas, write this block's partial row (coalesced, no atomics)
    for (int c = threadIdx.x; c < JBINS; c += 256) {
        unsigned int s = h[c] + h[RSTR + c] + h[2 * RSTR + c] + h[3 * RSTR + c];
        partials[(size_t)blockIdx.x * JBINS + c] = s;
    }
}

__global__ void __launch_bounds__(256) reduce_partials(
        const unsigned int* __restrict__ partials,
        unsigned int* __restrict__ g, int nblocks) {
    __shared__ unsigned int lds[256];
    const int c = blockIdx.x;  // one block per joint bin
    unsigned int s = 0;
    for (int b = threadIdx.x; b < nblocks; b += 256)
        s += partials[(size_t)b * JBINS + c];
    lds[threadIdx.x] = s;
    __syncthreads();
    for (int w = 128; w > 0; w >>= 1) {
        if (threadIdx.x < w) lds[threadIdx.x] += lds[threadIdx.x + w];
        __syncthreads();
    }
    if (threadIdx.x == 0) g[c] = lds[0];
}

__global__ void finalize_kernel(const unsigned int* __restrict__ g,
                                float* __restrict__ out) {
    int lane = threadIdx.x;  // single wave of 64
    float iou = 0.0f, pres = 0.0f;
    if (lane >= 1 && lane <= NUMC) {
        unsigned int ct = 0, cp = 0;
        #pragma unroll
        for (int k = 0; k < NBINS; k++) {
            ct += g[lane * NBINS + k];   // row sum: cnt_true[lane]
            cp += g[k * NBINS + lane];   // col sum: cnt_pred[lane]
        }
        unsigned int ci = g[lane * NBINS + lane];
        float u = (float)ct + (float)cp - (float)ci;
        iou = ((float)ci + 1e-6f) / (u + 1e-6f);
        pres = (ct > 0u) ? 1.0f : 0.0f;
        out[lane] = iou;  // out[1..21]
    }
    float v = iou * pres, pc = pres;
    #pragma unroll
    for (int off = 32; off > 0; off >>= 1) {
        v += __shfl_down(v, off);
        pc += __shfl_down(pc, off);
    }
    if (lane == 0) out[0] = v / fmaxf(pc, 1.0f);
}

extern "C" void kernel_launch(void* const* d_in, const int* in_sizes, int n_in,
                              void* d_out, int out_size, void* d_ws, size_t ws_size,
                              hipStream_t stream) {
    const int* yp = (const int*)d_in[0];
    const int* yt = (const int*)d_in[1];
    int n = in_sizes[0];
    float* out = (float*)d_out;

    // ws layout: g[484] | partials[GRID * 484]  (~4.0 MB)
    unsigned int* g = (unsigned int*)d_ws;
    unsigned int* partials = g + JBINS;

    hist_joint<<<GRID, 256, 0, stream>>>(yp, yt, partials, n);
    reduce_partials<<<JBINS, 256, 0, stream>>>(partials, g, GRID);
    finalize_kernel<<<1, 64, 0, stream>>>(g, out);
}